// Round 1
// baseline (1012.765 us; speedup 1.0000x reference)
//
#include <hip/hip_runtime.h>

// SlotAttention on MI355X (gfx950).
// Strategy: never materialize k/v. Per iteration:
//   logits[n,s] = rstd_n*(x_n . qg_s) + (rstd_n*mu_n)*c_s + d_s   (qg = g*(Wk q)/16, MFMA bf16)
//   Y[s,i]      = sum_n attn[n,s]*rstd_n*x[n,i]                   (vector FMA)
//   updates     = (g*(Y-S1) + b*S0)/(S0+1e-8) @ Wv                (tiny MFMA)
// Slot-sized math (GRU, MLP, LN, q, qk) in one per-batch kernel, fp32 elementwise,
// bf16 MFMA matmuls with B-operands stored K-contiguous (16B lane loads).

typedef unsigned short u16;
typedef __attribute__((ext_vector_type(8))) short bf16x8;
typedef __attribute__((ext_vector_type(4))) float f32x4;

#define MFMA16(a, b, c) __builtin_amdgcn_mfma_f32_16x16x32_bf16((a), (b), (c), 0, 0, 0)

__device__ __forceinline__ u16 f2bf(float f) {
  union { float f; unsigned u; } v; v.f = f;
  unsigned r = (v.u + 0x7fffu + ((v.u >> 16) & 1u)) >> 16;
  return (u16)r;
}
__device__ __forceinline__ float bf2f(u16 h) {
  union { unsigned u; float f; } v; v.u = ((unsigned)h) << 16;
  return v.f;
}
__device__ __forceinline__ float sigm(float x) { return 1.f / (1.f + __expf(-x)); }
__device__ __forceinline__ float tanh_f(float x) { return 1.f - 2.f / (1.f + __expf(2.f * x)); }

// ---------------------------------------------------------------- prep: cast/transpose weights to bf16
__global__ __launch_bounds__(256) void prep_kernel(
    const float* __restrict__ Wq, const float* __restrict__ Wk, const float* __restrict__ Wv,
    const float* __restrict__ wih, const float* __restrict__ whh,
    const float* __restrict__ w1, const float* __restrict__ w2,
    u16* __restrict__ wkB, u16* __restrict__ wqT, u16* __restrict__ wvT,
    u16* __restrict__ wihB, u16* __restrict__ whhB, u16* __restrict__ w1T, u16* __restrict__ w2T) {
  int gid = blockIdx.x * 256 + threadIdx.x;
  int stride = gridDim.x * 256;
  for (int i = gid; i < 65536; i += stride) wkB[i] = f2bf(Wk[i]);                      // [i][d] K=d
  for (int i = gid; i < 65536; i += stride) { int d = i >> 8, e = i & 255; wqT[i] = f2bf(Wq[e * 256 + d]); }   // [d][e]
  for (int i = gid; i < 65536; i += stride) { int d = i >> 8, ii = i & 255; wvT[i] = f2bf(Wv[ii * 256 + d]); } // [d][i]
  for (int i = gid; i < 196608; i += stride) wihB[i] = f2bf(wih[i]);                   // [j][d]
  for (int i = gid; i < 196608; i += stride) whhB[i] = f2bf(whh[i]);                   // [j][d]
  for (int i = gid; i < 262144; i += stride) { int j = i >> 8, e = i & 255; w1T[i] = f2bf(w1[e * 1024 + j]); } // [j][e]
  for (int i = gid; i < 262144; i += stride) { int d = i >> 10, j = i & 1023; w2T[i] = f2bf(w2[j * 256 + d]); } // [d][j]
}

// ---------------------------------------------------------------- LN over 8 rows (rows 8..15 of dst zeroed)
__device__ __forceinline__ void ln_rows8(const float (*src)[264], u16 (*dst)[264],
                                         const float* __restrict__ g, const float* __restrict__ bb,
                                         int wave, int lane) {
#pragma unroll
  for (int pass = 0; pass < 2; pass++) {
    int row = wave + pass * 4;
    float4 v = *reinterpret_cast<const float4*>(&src[row][lane * 4]);
    float s = v.x + v.y + v.z + v.w;
    float sq = v.x * v.x + v.y * v.y + v.z * v.z + v.w * v.w;
#pragma unroll
    for (int m = 1; m < 64; m <<= 1) { s += __shfl_xor(s, m); sq += __shfl_xor(sq, m); }
    float mu = s * (1.f / 256.f);
    float var = sq * (1.f / 256.f) - mu * mu;
    float rstd = rsqrtf(fmaxf(var, 0.f) + 1e-5f);
    float4 gg = *reinterpret_cast<const float4*>(&g[lane * 4]);
    float4 bv = *reinterpret_cast<const float4*>(&bb[lane * 4]);
    unsigned lo = (unsigned)f2bf((v.x - mu) * rstd * gg.x + bv.x) |
                  ((unsigned)f2bf((v.y - mu) * rstd * gg.y + bv.y) << 16);
    unsigned hi = (unsigned)f2bf((v.z - mu) * rstd * gg.z + bv.z) |
                  ((unsigned)f2bf((v.w - mu) * rstd * gg.w + bv.w) << 16);
    *reinterpret_cast<uint2*>(&dst[row][lane * 4]) = make_uint2(lo, hi);
    *reinterpret_cast<uint2*>(&dst[row + 8][lane * 4]) = make_uint2(0, 0);
  }
}

// ---------------------------------------------------------------- slot kernel: one block per batch
// do_update=0: init slots from mu+exp(ls)*noise, then compute qg/cd.
// do_update=1: reduce partials -> updates -> GRU -> MLP -> new slots (-> d_out), then qg/cd.
__global__ __launch_bounds__(256) void slot_kernel(
    float* __restrict__ slots, u16* __restrict__ qg, float* __restrict__ cd,
    const float* __restrict__ wsY, const float* __restrict__ wsS,
    const u16* __restrict__ wvT, const u16* __restrict__ wihB, const u16* __restrict__ whhB,
    const u16* __restrict__ w1T, const u16* __restrict__ w2T, const u16* __restrict__ wqT,
    const u16* __restrict__ wkB,
    const float* __restrict__ bih, const float* __restrict__ bhh,
    const float* __restrict__ b1v, const float* __restrict__ b2v,
    const float* __restrict__ g_in, const float* __restrict__ b_in,
    const float* __restrict__ g_s, const float* __restrict__ b_s,
    const float* __restrict__ g_m, const float* __restrict__ b_m,
    const float* __restrict__ s_mu, const float* __restrict__ s_ls,
    const float* __restrict__ noise,
    float* __restrict__ d_out, int do_update) {
  // LDS pool with aliasing (keep static LDS < 64KB)
  __shared__ alignas(16) char pool[58368];
  u16 (*h_lds)[1032] = reinterpret_cast<u16(*)[1032]>(pool);            // 33024 (P5->P6)
  u16 (*u_lds)[264] = reinterpret_cast<u16(*)[264]>(pool);              // alias h (P1->P2)
  u16 (*uv_lds)[264] = reinterpret_cast<u16(*)[264]>(pool + 8448);      // alias h (P2->P3)
  u16 (*sb_lds)[264] = reinterpret_cast<u16(*)[264]>(pool + 16896);     // alias h (P0->P3)
  u16 (*m_lds)[264] = reinterpret_cast<u16(*)[264]>(pool + 33024);      // 8448 (P4->P5, reused P7->P9)
  float (*ns_lds)[264] = reinterpret_cast<float(*)[264]>(pool + 41472); // 16896 (P3->P7)
  u16 (*q_lds)[264] = reinterpret_cast<u16(*)[264]>(pool + 41472);      // alias ns (P8->P9)
  __shared__ float sS0[16], sS1[16], sInv[16];
  __shared__ float redq[4][4][4][2];

  const int b = blockIdx.x;
  const int tid = threadIdx.x;
  const int lane = tid & 63, wave = tid >> 6;
  const int quad = lane >> 4, col = lane & 15;
  const f32x4 vzero = {0.f, 0.f, 0.f, 0.f};

  if (do_update) {
    // P0: reduce S partials; stage slots as bf16
    if (tid < 16) {
      float S0 = 0.f, S1 = 0.f;
      if (tid < 8) {
        for (int c = 0; c < 8; c++) {
          S0 += wsS[((b * 8 + c) * 8 + tid) * 2 + 0];
          S1 += wsS[((b * 8 + c) * 8 + tid) * 2 + 1];
        }
      }
      sS0[tid] = S0; sS1[tid] = S1; sInv[tid] = 1.f / (S0 + 1e-8f);
    }
    for (int s = 0; s < 16; s++)
      sb_lds[s][tid] = (s < 8) ? f2bf(slots[(size_t)(b * 8 + s) * 256 + tid]) : (u16)0;
    __syncthreads();
    // P1: u_hat (I-space updates)
    {
      float gv = g_in[tid], bv = b_in[tid];
      for (int s = 0; s < 8; s++) {
        float y = 0.f;
        for (int c = 0; c < 8; c++) y += wsY[((size_t)((b * 8 + c) * 8 + s)) * 256 + tid];
        float u = (gv * (y - sS1[s]) + bv * sS0[s]) * sInv[s];
        u_lds[s][tid] = f2bf(u);
      }
      for (int s = 8; s < 16; s++) u_lds[s][tid] = 0;
    }
    __syncthreads();
    // P2: updates_v = u_hat @ Wv  (B = wvT[d][i])
    {
      bf16x8 af[8];
#pragma unroll
      for (int k = 0; k < 8; k++)
        af[k] = *reinterpret_cast<const bf16x8*>(&u_lds[col][k * 32 + quad * 8]);
      for (int cc = 0; cc < 4; cc++) {
        int ct = wave * 4 + cc;
        f32x4 acc = vzero;
#pragma unroll
        for (int k = 0; k < 8; k++) {
          bf16x8 bf = *reinterpret_cast<const bf16x8*>(wvT + (size_t)(ct * 16 + col) * 256 + k * 32 + quad * 8);
          acc = MFMA16(af[k], bf, acc);
        }
#pragma unroll
        for (int r = 0; r < 4; r++) {
          int s = quad * 4 + r;
          uv_lds[s][ct * 16 + col] = (s < 8) ? f2bf(acc[r]) : (u16)0;
        }
      }
    }
    __syncthreads();
    // P3: gi/gh GEMMs + GRU elementwise -> ns_lds
    {
      bf16x8 afu[8], afs[8];
#pragma unroll
      for (int k = 0; k < 8; k++) {
        afu[k] = *reinterpret_cast<const bf16x8*>(&uv_lds[col][k * 32 + quad * 8]);
        afs[k] = *reinterpret_cast<const bf16x8*>(&sb_lds[col][k * 32 + quad * 8]);
      }
      for (int cc = 0; cc < 4; cc++) {
        int dt = wave * 4 + cc;
        int d = dt * 16 + col;
        f32x4 a_ir = vzero, a_iz = vzero, a_in = vzero, a_hr = vzero, a_hz = vzero, a_hn = vzero;
#pragma unroll
        for (int k = 0; k < 8; k++) {
          int ko = k * 32 + quad * 8;
          a_ir = MFMA16(afu[k], *reinterpret_cast<const bf16x8*>(wihB + (size_t)(d)*256 + ko), a_ir);
          a_iz = MFMA16(afu[k], *reinterpret_cast<const bf16x8*>(wihB + (size_t)(256 + d) * 256 + ko), a_iz);
          a_in = MFMA16(afu[k], *reinterpret_cast<const bf16x8*>(wihB + (size_t)(512 + d) * 256 + ko), a_in);
          a_hr = MFMA16(afs[k], *reinterpret_cast<const bf16x8*>(whhB + (size_t)(d)*256 + ko), a_hr);
          a_hz = MFMA16(afs[k], *reinterpret_cast<const bf16x8*>(whhB + (size_t)(256 + d) * 256 + ko), a_hz);
          a_hn = MFMA16(afs[k], *reinterpret_cast<const bf16x8*>(whhB + (size_t)(512 + d) * 256 + ko), a_hn);
        }
        float bihr = bih[d], bihz = bih[256 + d], bihn = bih[512 + d];
        float bhhr = bhh[d], bhhz = bhh[256 + d], bhhn = bhh[512 + d];
#pragma unroll
        for (int r = 0; r < 4; r++) {
          int s = quad * 4 + r;
          float rg = sigm(a_ir[r] + bihr + a_hr[r] + bhhr);
          float zg = sigm(a_iz[r] + bihz + a_hz[r] + bhhz);
          float ng = tanh_f(a_in[r] + bihn + rg * (a_hn[r] + bhhn));
          float prev = (s < 8) ? slots[(size_t)(b * 8 + s) * 256 + d] : 0.f;
          float ns = (1.f - zg) * ng + zg * prev;
          ns_lds[s][d] = (s < 8) ? ns : 0.f;
        }
      }
    }
    __syncthreads();
    // P4: LN_m -> m_lds
    ln_rows8(ns_lds, m_lds, g_m, b_m, wave, lane);
    __syncthreads();
    // P5: mlp1 -> h_lds (relu)
    {
      bf16x8 af[8];
#pragma unroll
      for (int k = 0; k < 8; k++)
        af[k] = *reinterpret_cast<const bf16x8*>(&m_lds[col][k * 32 + quad * 8]);
      for (int cc = 0; cc < 16; cc++) {
        int ct = wave * 16 + cc;
        f32x4 acc = vzero;
#pragma unroll
        for (int k = 0; k < 8; k++) {
          bf16x8 bf = *reinterpret_cast<const bf16x8*>(w1T + (size_t)(ct * 16 + col) * 256 + k * 32 + quad * 8);
          acc = MFMA16(af[k], bf, acc);
        }
        float bb = b1v[ct * 16 + col];
#pragma unroll
        for (int r = 0; r < 4; r++) {
          int s = quad * 4 + r;
          float h = fmaxf(acc[r] + bb, 0.f);
          h_lds[s][ct * 16 + col] = (s < 8) ? f2bf(h) : (u16)0;
        }
      }
    }
    __syncthreads();
    // P6: mlp2 + residual -> new slots (ws + d_out + ns_lds)
    {
      f32x4 acc[4];
      for (int cc = 0; cc < 4; cc++) acc[cc] = vzero;
      for (int k = 0; k < 32; k++) {
        bf16x8 af = *reinterpret_cast<const bf16x8*>(&h_lds[col][k * 32 + quad * 8]);
#pragma unroll
        for (int cc = 0; cc < 4; cc++) {
          int ct = wave * 4 + cc;
          bf16x8 bf = *reinterpret_cast<const bf16x8*>(w2T + (size_t)(ct * 16 + col) * 1024 + k * 32 + quad * 8);
          acc[cc] = MFMA16(af, bf, acc[cc]);
        }
      }
#pragma unroll
      for (int cc = 0; cc < 4; cc++) {
        int d = (wave * 4 + cc) * 16 + col;
        float bb = b2v[d];
#pragma unroll
        for (int r = 0; r < 4; r++) {
          int s = quad * 4 + r;
          if (s < 8) {
            float fin = ns_lds[s][d] + acc[cc][r] + bb;
            slots[(size_t)(b * 8 + s) * 256 + d] = fin;
            d_out[(size_t)(b * 8 + s) * 256 + d] = fin;
            ns_lds[s][d] = fin;
          }
        }
      }
    }
    __syncthreads();
  } else {
    // init: slots = mu + exp(ls)*noise
    for (int s = 0; s < 16; s++) {
      float v = 0.f;
      if (s < 8) {
        v = s_mu[tid] + __expf(s_ls[tid]) * noise[(size_t)(b * 8 + s) * 256 + tid];
        slots[(size_t)(b * 8 + s) * 256 + tid] = v;
      }
      ns_lds[s][tid] = v;
    }
    __syncthreads();
  }

  // ---- TAIL: qg/cd for next attention pass ----
  // P7: LN_s -> m_lds
  ln_rows8(ns_lds, m_lds, g_s, b_s, wave, lane);
  __syncthreads();
  // P8: q = s_n @ Wq -> q_lds
  {
    bf16x8 af[8];
#pragma unroll
    for (int k = 0; k < 8; k++)
      af[k] = *reinterpret_cast<const bf16x8*>(&m_lds[col][k * 32 + quad * 8]);
    for (int cc = 0; cc < 4; cc++) {
      int ct = wave * 4 + cc;
      f32x4 acc = vzero;
#pragma unroll
      for (int k = 0; k < 8; k++) {
        bf16x8 bf = *reinterpret_cast<const bf16x8*>(wqT + (size_t)(ct * 16 + col) * 256 + k * 32 + quad * 8);
        acc = MFMA16(af[k], bf, acc);
      }
#pragma unroll
      for (int r = 0; r < 4; r++) {
        int s = quad * 4 + r;
        q_lds[s][ct * 16 + col] = (s < 8) ? f2bf(acc[r]) : (u16)0;
      }
    }
  }
  __syncthreads();
  // P9: qk = q @ Wk^T-as-B; qg = g*qk/16; c = -sum qg; d = sum b*qk/16
  {
    bf16x8 af[8];
#pragma unroll
    for (int k = 0; k < 8; k++)
      af[k] = *reinterpret_cast<const bf16x8*>(&q_lds[col][k * 32 + quad * 8]);
    float cacc[4] = {0.f, 0.f, 0.f, 0.f}, dacc[4] = {0.f, 0.f, 0.f, 0.f};
    for (int cc = 0; cc < 4; cc++) {
      int ct = wave * 4 + cc;
      f32x4 acc = vzero;
#pragma unroll
      for (int k = 0; k < 8; k++) {
        bf16x8 bf = *reinterpret_cast<const bf16x8*>(wkB + (size_t)(ct * 16 + col) * 256 + k * 32 + quad * 8);
        acc = MFMA16(af[k], bf, acc);
      }
      int i = ct * 16 + col;
      float gi_ = g_in[i] * 0.0625f, bi_ = b_in[i] * 0.0625f;
#pragma unroll
      for (int r = 0; r < 4; r++) {
        int s = quad * 4 + r;
        float qkv = acc[r];
        float qgv = (s < 8) ? gi_ * qkv : 0.f;
        qg[(size_t)(b * 16 + s) * 256 + i] = f2bf(qgv);
        cacc[r] -= qgv;
        dacc[r] += (s < 8) ? bi_ * qkv : 0.f;
      }
    }
#pragma unroll
    for (int r = 0; r < 4; r++) {
#pragma unroll
      for (int m = 1; m < 16; m <<= 1) {
        cacc[r] += __shfl_xor(cacc[r], m);
        dacc[r] += __shfl_xor(dacc[r], m);
      }
    }
    if (col == 0) {
#pragma unroll
      for (int r = 0; r < 4; r++) {
        redq[wave][quad][r][0] = cacc[r];
        redq[wave][quad][r][1] = dacc[r];
      }
    }
    __syncthreads();
    if (tid < 16) {
      int qd = tid >> 2, r = tid & 3;
      float c = 0.f, dd = 0.f;
      for (int w = 0; w < 4; w++) { c += redq[w][qd][r][0]; dd += redq[w][qd][r][1]; }
      cd[(b * 16 + tid) * 2 + 0] = c;
      cd[(b * 16 + tid) * 2 + 1] = dd;
    }
  }
}

// ---------------------------------------------------------------- attention kernel
// grid (8 chunks, 64 batches), 256 threads. Each block: 512 n's in 8 groups of 64.
__global__ __launch_bounds__(256) void attn_kernel(
    const float* __restrict__ x, const u16* __restrict__ qg, const float* __restrict__ cd,
    float* __restrict__ out, float* __restrict__ wsY, float* __restrict__ wsS) {
  __shared__ alignas(16) u16 x_lds[64][264];
  __shared__ alignas(16) float attn_lds[64][12];
  __shared__ float2 stats_lds[64];
  __shared__ float2 red2[4][8];

  const int chunk = blockIdx.x, b = blockIdx.y;
  const int tid = threadIdx.x;
  const int lane = tid & 63, wave = tid >> 6;
  const int quad = lane >> 4, col = lane & 15;

  // hoist q-fragments (constant for whole block) + per-slot scalars
  bf16x8 bfrag[8];
#pragma unroll
  for (int k = 0; k < 8; k++)
    bfrag[k] = *reinterpret_cast<const bf16x8*>(qg + (size_t)(b * 16 + col) * 256 + k * 32 + quad * 8);
  const float2 cdv = *reinterpret_cast<const float2*>(cd + (b * 16 + col) * 2);

  float Y[8];
#pragma unroll
  for (int s = 0; s < 8; s++) Y[s] = 0.f;
  float s0a = 0.f, s1a = 0.f;
  float* out_attn = out + 131072;

  for (int g = 0; g < 8; g++) {
    const int nb = chunk * 512 + g * 64;
    // stage 64 rows of x: fp32 -> bf16 LDS + row stats (rstd, rstd*mu)
#pragma unroll 4
    for (int p = 0; p < 16; p++) {
      int row = p * 4 + wave;
      const float4 v = *reinterpret_cast<const float4*>(x + (size_t)(b * 4096 + nb + row) * 256 + lane * 4);
      float s = v.x + v.y + v.z + v.w;
      float sq = v.x * v.x + v.y * v.y + v.z * v.z + v.w * v.w;
#pragma unroll
      for (int m = 1; m < 64; m <<= 1) { s += __shfl_xor(s, m); sq += __shfl_xor(sq, m); }
      float mu = s * (1.f / 256.f);
      float var = sq * (1.f / 256.f) - mu * mu;
      float rstd = rsqrtf(fmaxf(var, 0.f) + 1e-5f);
      if (lane == 0) stats_lds[row] = make_float2(rstd, rstd * mu);
      unsigned lo = (unsigned)f2bf(v.x) | ((unsigned)f2bf(v.y) << 16);
      unsigned hi = (unsigned)f2bf(v.z) | ((unsigned)f2bf(v.w) << 16);
      *reinterpret_cast<uint2*>(&x_lds[row][lane * 4]) = make_uint2(lo, hi);
    }
    __syncthreads();
    // phase A: logits MFMA + softmax over 8 slots + attn out + a2 to LDS
    {
      const int rowbase = wave * 16;
      f32x4 acc = {0.f, 0.f, 0.f, 0.f};
#pragma unroll
      for (int k = 0; k < 8; k++) {
        bf16x8 af = *reinterpret_cast<const bf16x8*>(&x_lds[rowbase + col][k * 32 + quad * 8]);
        acc = MFMA16(af, bfrag[k], acc);
      }
      float at[4], rmx[4], rmy[4];
#pragma unroll
      for (int r = 0; r < 4; r++) {
        float2 rm = stats_lds[rowbase + quad * 4 + r];
        rmx[r] = rm.x; rmy[r] = rm.y;
        float lg = rm.x * acc[r] + rm.y * cdv.x + cdv.y;
        float mx = lg;
        mx = fmaxf(mx, __shfl_xor(mx, 1));
        mx = fmaxf(mx, __shfl_xor(mx, 2));
        mx = fmaxf(mx, __shfl_xor(mx, 4));
        float e = __expf(lg - mx);
        float sm = e;
        sm += __shfl_xor(sm, 1); sm += __shfl_xor(sm, 2); sm += __shfl_xor(sm, 4);
        at[r] = e / sm;
      }
      if (col < 8) {
#pragma unroll
        for (int r = 0; r < 4; r++) {
          int n_loc = rowbase + quad * 4 + r;
          out_attn[(size_t)(b * 8 + col) * 4096 + nb + n_loc] = at[r];
          attn_lds[n_loc][col] = at[r] * rmx[r];  // a2 = attn*rstd
          s0a += at[r];
          s1a += at[r] * rmy[r];
        }
      }
    }
    __syncthreads();
    // phase B: Y[s, i=tid] += a2[n,s] * x_bf16[n, tid]
#pragma unroll 2
    for (int n = 0; n < 64; n++) {
      const float4 a0 = *reinterpret_cast<const float4*>(&attn_lds[n][0]);
      const float4 a1 = *reinterpret_cast<const float4*>(&attn_lds[n][4]);
      float xv = bf2f(x_lds[n][tid]);
      Y[0] += a0.x * xv; Y[1] += a0.y * xv; Y[2] += a0.z * xv; Y[3] += a0.w * xv;
      Y[4] += a1.x * xv; Y[5] += a1.y * xv; Y[6] += a1.z * xv; Y[7] += a1.w * xv;
    }
    __syncthreads();
  }
  // epilogue: store partials
#pragma unroll
  for (int s = 0; s < 8; s++)
    wsY[(size_t)((b * 8 + chunk) * 8 + s) * 256 + tid] = Y[s];
  s0a += __shfl_xor(s0a, 16); s0a += __shfl_xor(s0a, 32);
  s1a += __shfl_xor(s1a, 16); s1a += __shfl_xor(s1a, 32);
  if (lane < 8) red2[wave][lane] = make_float2(s0a, s1a);
  __syncthreads();
  if (tid < 8) {
    float S0 = 0.f, S1 = 0.f;
#pragma unroll
    for (int w = 0; w < 4; w++) { S0 += red2[w][tid].x; S1 += red2[w][tid].y; }
    wsS[((b * 8 + chunk) * 8 + tid) * 2 + 0] = S0;
    wsS[((b * 8 + chunk) * 8 + tid) * 2 + 1] = S1;
  }
}

// ---------------------------------------------------------------- launch
extern "C" void kernel_launch(void* const* d_in, const int* in_sizes, int n_in,
                              void* d_out, int out_size, void* d_ws, size_t ws_size,
                              hipStream_t stream) {
  const float* inputs = (const float*)d_in[0];
  const float* noise = (const float*)d_in[1];
  const float* s_mu = (const float*)d_in[2];
  const float* s_ls = (const float*)d_in[3];
  const float* g_in = (const float*)d_in[4];
  const float* b_in = (const float*)d_in[5];
  const float* g_s = (const float*)d_in[6];
  const float* b_s = (const float*)d_in[7];
  const float* g_m = (const float*)d_in[8];
  const float* b_m = (const float*)d_in[9];
  const float* Wq = (const float*)d_in[10];
  const float* Wk = (const float*)d_in[11];
  const float* Wv = (const float*)d_in[12];
  const float* wih = (const float*)d_in[13];
  const float* whh = (const float*)d_in[14];
  const float* bih = (const float*)d_in[15];
  const float* bhh = (const float*)d_in[16];
  const float* w1 = (const float*)d_in[17];
  const float* b1v = (const float*)d_in[18];
  const float* w2 = (const float*)d_in[19];
  const float* b2v = (const float*)d_in[20];
  float* out = (float*)d_out;

  size_t o = 0;
  auto take = [&](size_t bytes) {
    void* p = (char*)d_ws + o;
    o += (bytes + 255) & ~(size_t)255;
    return p;
  };
  float* slots = (float*)take((size_t)64 * 8 * 256 * 4);
  u16* qg = (u16*)take((size_t)64 * 16 * 256 * 2);
  float* cd = (float*)take((size_t)64 * 16 * 2 * 4);
  float* wsY = (float*)take((size_t)64 * 8 * 8 * 256 * 4);
  float* wsS = (float*)take((size_t)64 * 8 * 8 * 2 * 4);
  u16* wkB = (u16*)take((size_t)65536 * 2);
  u16* wqT = (u16*)take((size_t)65536 * 2);
  u16* wvT = (u16*)take((size_t)65536 * 2);
  u16* wihB = (u16*)take((size_t)196608 * 2);
  u16* whhB = (u16*)take((size_t)196608 * 2);
  u16* w1T = (u16*)take((size_t)262144 * 2);
  u16* w2T = (u16*)take((size_t)262144 * 2);

  prep_kernel<<<256, 256, 0, stream>>>(Wq, Wk, Wv, wih, whh, w1, w2,
                                       wkB, wqT, wvT, wihB, whhB, w1T, w2T);
  slot_kernel<<<64, 256, 0, stream>>>(slots, qg, cd, wsY, wsS,
                                      wvT, wihB, whhB, w1T, w2T, wqT, wkB,
                                      bih, bhh, b1v, b2v,
                                      g_in, b_in, g_s, b_s, g_m, b_m,
                                      s_mu, s_ls, noise, out, 0);
  for (int it = 0; it < 3; it++) {
    attn_kernel<<<dim3(8, 64), 256, 0, stream>>>(inputs, qg, cd, out, wsY, wsS);
    slot_kernel<<<64, 256, 0, stream>>>(slots, qg, cd, wsY, wsS,
                                        wvT, wihB, whhB, w1T, w2T, wqT, wkB,
                                        bih, bhh, b1v, b2v,
                                        g_in, b_in, g_s, b_s, g_m, b_m,
                                        s_mu, s_ls, noise, out, 1);
  }
}

// Round 2
// 773.068 us; speedup vs baseline: 1.3101x; 1.3101x over previous
//
#include <hip/hip_runtime.h>

// SlotAttention on MI355X (gfx950).
// Never materialize k/v:
//   logits[n,s] = rstd_n*(x_n . qg_s) + (rstd_n*mu_n)*c_s + d_s   (qg = g*(Wk q)/16, MFMA bf16)
//   Y[s,i]      = sum_n attn[n,s]*rstd_n*x[n,i]                   (MFMA: A=a2^T, B=x columns)
//   updates     = (g*(Y-S1) + b*S0)/(S0+1e-8) @ Wv                (tiny MFMA)
// attn: 512-thread blocks, 2 blocks/CU (16 waves/CU); register-prefetched staging.
// slot: 1024-thread blocks (16 waves), one 16-col tile per wave per GEMM phase.

typedef unsigned short u16;
typedef __attribute__((ext_vector_type(8))) short bf16x8;
typedef __attribute__((ext_vector_type(4))) float f32x4;

#define MFMA16(a, b, c) __builtin_amdgcn_mfma_f32_16x16x32_bf16((a), (b), (c), 0, 0, 0)

__device__ __forceinline__ u16 f2bf(float f) {
  union { float f; unsigned u; } v; v.f = f;
  unsigned r = (v.u + 0x7fffu + ((v.u >> 16) & 1u)) >> 16;
  return (u16)r;
}
__device__ __forceinline__ float sigm(float x) { return 1.f / (1.f + __expf(-x)); }
__device__ __forceinline__ float tanh_f(float x) { return 1.f - 2.f / (1.f + __expf(2.f * x)); }

// ---------------------------------------------------------------- prep: cast/transpose weights to bf16
__global__ __launch_bounds__(256) void prep_kernel(
    const float* __restrict__ Wq, const float* __restrict__ Wk, const float* __restrict__ Wv,
    const float* __restrict__ wih, const float* __restrict__ whh,
    const float* __restrict__ w1, const float* __restrict__ w2,
    u16* __restrict__ wkB, u16* __restrict__ wqT, u16* __restrict__ wvT,
    u16* __restrict__ wihB, u16* __restrict__ whhB, u16* __restrict__ w1T, u16* __restrict__ w2T) {
  int gid = blockIdx.x * 256 + threadIdx.x;
  int stride = gridDim.x * 256;
  for (int i = gid; i < 65536; i += stride) wkB[i] = f2bf(Wk[i]);                      // [i][d] K=d
  for (int i = gid; i < 65536; i += stride) { int d = i >> 8, e = i & 255; wqT[i] = f2bf(Wq[e * 256 + d]); }
  for (int i = gid; i < 65536; i += stride) { int d = i >> 8, ii = i & 255; wvT[i] = f2bf(Wv[ii * 256 + d]); }
  for (int i = gid; i < 196608; i += stride) wihB[i] = f2bf(wih[i]);
  for (int i = gid; i < 196608; i += stride) whhB[i] = f2bf(whh[i]);
  for (int i = gid; i < 262144; i += stride) { int j = i >> 8, e = i & 255; w1T[i] = f2bf(w1[e * 1024 + j]); }
  for (int i = gid; i < 262144; i += stride) { int d = i >> 10, j = i & 1023; w2T[i] = f2bf(w2[j * 256 + d]); }
}

// ---------------------------------------------------------------- per-wave LN of one row (wave=row), rows 8..15 zeroed
__device__ __forceinline__ void ln_row16(const float (*src)[264], u16 (*dst)[264],
                                         const float* __restrict__ g, const float* __restrict__ bb,
                                         int wave, int lane) {
  int row = wave;
  if (row < 8) {
    float4 v = *reinterpret_cast<const float4*>(&src[row][lane * 4]);
    float s = v.x + v.y + v.z + v.w;
    float sq = v.x * v.x + v.y * v.y + v.z * v.z + v.w * v.w;
#pragma unroll
    for (int m = 1; m < 64; m <<= 1) { s += __shfl_xor(s, m); sq += __shfl_xor(sq, m); }
    float mu = s * (1.f / 256.f);
    float var = sq * (1.f / 256.f) - mu * mu;
    float rstd = rsqrtf(fmaxf(var, 0.f) + 1e-5f);
    float4 gg = *reinterpret_cast<const float4*>(&g[lane * 4]);
    float4 bv = *reinterpret_cast<const float4*>(&bb[lane * 4]);
    unsigned lo = (unsigned)f2bf((v.x - mu) * rstd * gg.x + bv.x) |
                  ((unsigned)f2bf((v.y - mu) * rstd * gg.y + bv.y) << 16);
    unsigned hi = (unsigned)f2bf((v.z - mu) * rstd * gg.z + bv.z) |
                  ((unsigned)f2bf((v.w - mu) * rstd * gg.w + bv.w) << 16);
    *reinterpret_cast<uint2*>(&dst[row][lane * 4]) = make_uint2(lo, hi);
  } else if (row < 16) {
    *reinterpret_cast<uint2*>(&dst[row][lane * 4]) = make_uint2(0, 0);
  }
}

// ---------------------------------------------------------------- slot kernel: one block (1024 thr, 16 waves) per batch
__global__ __launch_bounds__(1024, 4) void slot_kernel(
    float* __restrict__ slots, u16* __restrict__ qg, float* __restrict__ cd,
    const float* __restrict__ wsY, const float* __restrict__ wsS,
    const u16* __restrict__ wvT, const u16* __restrict__ wihB, const u16* __restrict__ whhB,
    const u16* __restrict__ w1T, const u16* __restrict__ w2T, const u16* __restrict__ wqT,
    const u16* __restrict__ wkB,
    const float* __restrict__ bih, const float* __restrict__ bhh,
    const float* __restrict__ b1v, const float* __restrict__ b2v,
    const float* __restrict__ g_in, const float* __restrict__ b_in,
    const float* __restrict__ g_s, const float* __restrict__ b_s,
    const float* __restrict__ g_m, const float* __restrict__ b_m,
    const float* __restrict__ s_mu, const float* __restrict__ s_ls,
    const float* __restrict__ noise,
    float* __restrict__ d_out, int do_update) {
  __shared__ alignas(16) char pool[58368];
  u16 (*h_lds)[1032] = reinterpret_cast<u16(*)[1032]>(pool);            // 33024 (P5->P6)
  u16 (*u_lds)[264] = reinterpret_cast<u16(*)[264]>(pool);              // alias h (P1->P2)
  u16 (*uv_lds)[264] = reinterpret_cast<u16(*)[264]>(pool + 8448);      // alias h (P2->P3)
  u16 (*sb_lds)[264] = reinterpret_cast<u16(*)[264]>(pool + 16896);     // alias h (P0->P3)
  u16 (*m_lds)[264] = reinterpret_cast<u16(*)[264]>(pool + 33024);      // 8448 (P4->P5, reused P7->P9)
  float (*ns_lds)[264] = reinterpret_cast<float(*)[264]>(pool + 41472); // 16896 (P3->P7)
  u16 (*q_lds)[264] = reinterpret_cast<u16(*)[264]>(pool + 41472);      // alias ns (P8->P9)
  __shared__ float sS0[16], sS1[16], sInv[16];
  __shared__ float redq[16][4][4][2];

  const int b = blockIdx.x;
  const int tid = threadIdx.x;
  const int lane = tid & 63, wave = tid >> 6;
  const int quad = lane >> 4, col = lane & 15;
  const int i256 = tid & 255, s4 = tid >> 8;
  const f32x4 vzero = {0.f, 0.f, 0.f, 0.f};

  if (do_update) {
    // P0: reduce S partials; stage slots as bf16
    if (tid < 16) {
      float S0 = 0.f, S1 = 0.f;
      if (tid < 8) {
        for (int c = 0; c < 8; c++) {
          S0 += wsS[((b * 8 + c) * 8 + tid) * 2 + 0];
          S1 += wsS[((b * 8 + c) * 8 + tid) * 2 + 1];
        }
      }
      sS0[tid] = S0; sS1[tid] = S1; sInv[tid] = 1.f / (S0 + 1e-8f);
    }
#pragma unroll
    for (int r = 0; r < 4; r++) {
      int s = s4 + r * 4;
      sb_lds[s][i256] = (s < 8) ? f2bf(slots[(size_t)(b * 8 + s) * 256 + i256]) : (u16)0;
    }
    __syncthreads();
    // P1: u_hat (I-space updates)
    {
      float gv = g_in[i256], bv = b_in[i256];
#pragma unroll
      for (int r = 0; r < 4; r++) {
        int s = s4 + r * 4;
        if (s < 8) {
          float y = 0.f;
#pragma unroll
          for (int c = 0; c < 8; c++) y += wsY[((size_t)((b * 8 + c) * 8 + s)) * 256 + i256];
          u_lds[s][i256] = f2bf((gv * (y - sS1[s]) + bv * sS0[s]) * sInv[s]);
        } else {
          u_lds[s][i256] = 0;
        }
      }
    }
    __syncthreads();
    // P2: updates_v = u_hat @ Wv (one 16-col tile per wave)
    {
      bf16x8 af[8];
#pragma unroll
      for (int k = 0; k < 8; k++)
        af[k] = *reinterpret_cast<const bf16x8*>(&u_lds[col][k * 32 + quad * 8]);
      int ct = wave;
      f32x4 acc = vzero;
#pragma unroll
      for (int k = 0; k < 8; k++) {
        bf16x8 bf = *reinterpret_cast<const bf16x8*>(wvT + (size_t)(ct * 16 + col) * 256 + k * 32 + quad * 8);
        acc = MFMA16(af[k], bf, acc);
      }
#pragma unroll
      for (int r = 0; r < 4; r++) {
        int s = quad * 4 + r;
        uv_lds[s][ct * 16 + col] = (s < 8) ? f2bf(acc[r]) : (u16)0;
      }
    }
    __syncthreads();
    // P3: gi/gh GEMMs + GRU elementwise -> ns_lds (one d-tile per wave)
    {
      bf16x8 afu[8], afs[8];
#pragma unroll
      for (int k = 0; k < 8; k++) {
        afu[k] = *reinterpret_cast<const bf16x8*>(&uv_lds[col][k * 32 + quad * 8]);
        afs[k] = *reinterpret_cast<const bf16x8*>(&sb_lds[col][k * 32 + quad * 8]);
      }
      int d = wave * 16 + col;
      f32x4 a_ir = vzero, a_iz = vzero, a_in = vzero, a_hr = vzero, a_hz = vzero, a_hn = vzero;
#pragma unroll
      for (int k = 0; k < 8; k++) {
        int ko = k * 32 + quad * 8;
        a_ir = MFMA16(afu[k], *reinterpret_cast<const bf16x8*>(wihB + (size_t)(d)*256 + ko), a_ir);
        a_iz = MFMA16(afu[k], *reinterpret_cast<const bf16x8*>(wihB + (size_t)(256 + d) * 256 + ko), a_iz);
        a_in = MFMA16(afu[k], *reinterpret_cast<const bf16x8*>(wihB + (size_t)(512 + d) * 256 + ko), a_in);
        a_hr = MFMA16(afs[k], *reinterpret_cast<const bf16x8*>(whhB + (size_t)(d)*256 + ko), a_hr);
        a_hz = MFMA16(afs[k], *reinterpret_cast<const bf16x8*>(whhB + (size_t)(256 + d) * 256 + ko), a_hz);
        a_hn = MFMA16(afs[k], *reinterpret_cast<const bf16x8*>(whhB + (size_t)(512 + d) * 256 + ko), a_hn);
      }
      float bihr = bih[d], bihz = bih[256 + d], bihn = bih[512 + d];
      float bhhr = bhh[d], bhhz = bhh[256 + d], bhhn = bhh[512 + d];
#pragma unroll
      for (int r = 0; r < 4; r++) {
        int s = quad * 4 + r;
        float rg = sigm(a_ir[r] + bihr + a_hr[r] + bhhr);
        float zg = sigm(a_iz[r] + bihz + a_hz[r] + bhhz);
        float ng = tanh_f(a_in[r] + bihn + rg * (a_hn[r] + bhhn));
        float prev = (s < 8) ? slots[(size_t)(b * 8 + s) * 256 + d] : 0.f;
        float ns = (1.f - zg) * ng + zg * prev;
        ns_lds[s][d] = (s < 8) ? ns : 0.f;
      }
    }
    __syncthreads();
    // P4: LN_m -> m_lds
    ln_row16(ns_lds, m_lds, g_m, b_m, wave, lane);
    __syncthreads();
    // P5: mlp1 -> h_lds (relu), 4 tiles per wave
    {
      bf16x8 af[8];
#pragma unroll
      for (int k = 0; k < 8; k++)
        af[k] = *reinterpret_cast<const bf16x8*>(&m_lds[col][k * 32 + quad * 8]);
      for (int cc = 0; cc < 4; cc++) {
        int ct = wave * 4 + cc;
        f32x4 acc = vzero;
#pragma unroll
        for (int k = 0; k < 8; k++) {
          bf16x8 bf = *reinterpret_cast<const bf16x8*>(w1T + (size_t)(ct * 16 + col) * 256 + k * 32 + quad * 8);
          acc = MFMA16(af[k], bf, acc);
        }
        float bb = b1v[ct * 16 + col];
#pragma unroll
        for (int r = 0; r < 4; r++) {
          int s = quad * 4 + r;
          float h = fmaxf(acc[r] + bb, 0.f);
          h_lds[s][ct * 16 + col] = (s < 8) ? f2bf(h) : (u16)0;
        }
      }
    }
    __syncthreads();
    // P6: mlp2 + residual -> new slots (one tile per wave)
    {
      int ct = wave;
      f32x4 acc = vzero;
      for (int k = 0; k < 32; k++) {
        bf16x8 af = *reinterpret_cast<const bf16x8*>(&h_lds[col][k * 32 + quad * 8]);
        bf16x8 bf = *reinterpret_cast<const bf16x8*>(w2T + (size_t)(ct * 16 + col) * 1024 + k * 32 + quad * 8);
        acc = MFMA16(af, bf, acc);
      }
      int d = ct * 16 + col;
      float bb = b2v[d];
#pragma unroll
      for (int r = 0; r < 4; r++) {
        int s = quad * 4 + r;
        if (s < 8) {
          float fin = ns_lds[s][d] + acc[r] + bb;
          slots[(size_t)(b * 8 + s) * 256 + d] = fin;
          d_out[(size_t)(b * 8 + s) * 256 + d] = fin;
          ns_lds[s][d] = fin;
        }
      }
    }
    __syncthreads();
  } else {
    // init: slots = mu + exp(ls)*noise
#pragma unroll
    for (int r = 0; r < 4; r++) {
      int s = s4 + r * 4;
      float v = 0.f;
      if (s < 8) {
        v = s_mu[i256] + __expf(s_ls[i256]) * noise[(size_t)(b * 8 + s) * 256 + i256];
        slots[(size_t)(b * 8 + s) * 256 + i256] = v;
      }
      ns_lds[s][i256] = v;
    }
    __syncthreads();
  }

  // ---- TAIL: qg/cd for next attention pass ----
  // P7: LN_s -> m_lds
  ln_row16(ns_lds, m_lds, g_s, b_s, wave, lane);
  __syncthreads();
  // P8: q = s_n @ Wq -> q_lds (one tile per wave)
  {
    bf16x8 af[8];
#pragma unroll
    for (int k = 0; k < 8; k++)
      af[k] = *reinterpret_cast<const bf16x8*>(&m_lds[col][k * 32 + quad * 8]);
    int ct = wave;
    f32x4 acc = vzero;
#pragma unroll
    for (int k = 0; k < 8; k++) {
      bf16x8 bf = *reinterpret_cast<const bf16x8*>(wqT + (size_t)(ct * 16 + col) * 256 + k * 32 + quad * 8);
      acc = MFMA16(af[k], bf, acc);
    }
#pragma unroll
    for (int r = 0; r < 4; r++) {
      int s = quad * 4 + r;
      q_lds[s][ct * 16 + col] = (s < 8) ? f2bf(acc[r]) : (u16)0;
    }
  }
  __syncthreads();
  // P9: qk = q @ Wk-as-B; qg = g*qk/16; c = -sum qg; d = sum b*qk/16
  {
    bf16x8 af[8];
#pragma unroll
    for (int k = 0; k < 8; k++)
      af[k] = *reinterpret_cast<const bf16x8*>(&q_lds[col][k * 32 + quad * 8]);
    float cacc[4] = {0.f, 0.f, 0.f, 0.f}, dacc[4] = {0.f, 0.f, 0.f, 0.f};
    int ct = wave;
    f32x4 acc = vzero;
#pragma unroll
    for (int k = 0; k < 8; k++) {
      bf16x8 bf = *reinterpret_cast<const bf16x8*>(wkB + (size_t)(ct * 16 + col) * 256 + k * 32 + quad * 8);
      acc = MFMA16(af[k], bf, acc);
    }
    int i = ct * 16 + col;
    float gi_ = g_in[i] * 0.0625f, bi_ = b_in[i] * 0.0625f;
#pragma unroll
    for (int r = 0; r < 4; r++) {
      int s = quad * 4 + r;
      float qkv = acc[r];
      float qgv = (s < 8) ? gi_ * qkv : 0.f;
      qg[(size_t)(b * 16 + s) * 256 + i] = f2bf(qgv);
      cacc[r] -= qgv;
      dacc[r] += (s < 8) ? bi_ * qkv : 0.f;
    }
#pragma unroll
    for (int r = 0; r < 4; r++) {
#pragma unroll
      for (int m = 1; m < 16; m <<= 1) {
        cacc[r] += __shfl_xor(cacc[r], m);
        dacc[r] += __shfl_xor(dacc[r], m);
      }
    }
    if (col == 0) {
#pragma unroll
      for (int r = 0; r < 4; r++) {
        redq[wave][quad][r][0] = cacc[r];
        redq[wave][quad][r][1] = dacc[r];
      }
    }
    __syncthreads();
    if (tid < 16) {
      int qd = tid >> 2, r = tid & 3;
      float c = 0.f, dd = 0.f;
      for (int w = 0; w < 16; w++) { c += redq[w][qd][r][0]; dd += redq[w][qd][r][1]; }
      cd[(b * 16 + tid) * 2 + 0] = c;
      cd[(b * 16 + tid) * 2 + 1] = dd;
    }
  }
}

// ---------------------------------------------------------------- attention kernel
// grid (8 chunks, 64 batches), 512 threads (8 waves). Each block: 512 n's in 8 groups of 64.
__global__ __launch_bounds__(512, 4) void attn_kernel(
    const float* __restrict__ x, const u16* __restrict__ qg, const float* __restrict__ cd,
    float* __restrict__ out, float* __restrict__ wsY, float* __restrict__ wsS) {
  __shared__ alignas(16) u16 x_lds[64][264];
  __shared__ alignas(16) u16 a2t[16][72];   // a2^T: [slot][n_local], bf16
  __shared__ float2 stats_lds[64];
  __shared__ float2 red2[4][8];

  const int chunk = blockIdx.x, b = blockIdx.y;
  const int tid = threadIdx.x;
  const int lane = tid & 63, wave = tid >> 6;   // 8 waves
  const int quad = lane >> 4, col = lane & 15;

  // zero a2t rows 8..15 once (so A-fragment garbage rows are benign-by-construction)
  for (int idx = tid; idx < 288; idx += 512)
    reinterpret_cast<unsigned*>(&a2t[8][0])[idx] = 0;

  // hoist q-fragments (phase A B-operand) + per-slot scalars
  bf16x8 bfrag[8];
#pragma unroll
  for (int k = 0; k < 8; k++)
    bfrag[k] = *reinterpret_cast<const bf16x8*>(qg + (size_t)(b * 16 + col) * 256 + k * 32 + quad * 8);
  const float2 cdv = *reinterpret_cast<const float2*>(cd + (b * 16 + col) * 2);

  f32x4 Yacc[2];
  Yacc[0] = {0.f, 0.f, 0.f, 0.f};
  Yacc[1] = {0.f, 0.f, 0.f, 0.f};
  float s0a = 0.f, s1a = 0.f;
  float* out_attn = out + 131072;

  for (int g = 0; g < 8; g++) {
    const int nb = chunk * 512 + g * 64;
    // stage 64 rows: register-prefetch 8 rows/wave, then stats + bf16 LDS
    float4 vreg[8];
#pragma unroll
    for (int p = 0; p < 8; p++)
      vreg[p] = *reinterpret_cast<const float4*>(x + (size_t)(b * 4096 + nb + wave * 8 + p) * 256 + lane * 4);
#pragma unroll
    for (int p = 0; p < 8; p++) {
      int row = wave * 8 + p;
      float4 v = vreg[p];
      float s = v.x + v.y + v.z + v.w;
      float sq = v.x * v.x + v.y * v.y + v.z * v.z + v.w * v.w;
#pragma unroll
      for (int m = 1; m < 64; m <<= 1) { s += __shfl_xor(s, m); sq += __shfl_xor(sq, m); }
      float mu = s * (1.f / 256.f);
      float var = sq * (1.f / 256.f) - mu * mu;
      float rstd = rsqrtf(fmaxf(var, 0.f) + 1e-5f);
      if (lane == 0) stats_lds[row] = make_float2(rstd, rstd * mu);
      unsigned lo = (unsigned)f2bf(v.x) | ((unsigned)f2bf(v.y) << 16);
      unsigned hi = (unsigned)f2bf(v.z) | ((unsigned)f2bf(v.w) << 16);
      *reinterpret_cast<uint2*>(&x_lds[row][lane * 4]) = make_uint2(lo, hi);
    }
    __syncthreads();
    // phase A (waves 0..3): logits MFMA + softmax + attn out + a2t
    if (wave < 4) {
      const int rowbase = wave * 16;
      f32x4 acc = {0.f, 0.f, 0.f, 0.f};
#pragma unroll
      for (int k = 0; k < 8; k++) {
        bf16x8 af = *reinterpret_cast<const bf16x8*>(&x_lds[rowbase + col][k * 32 + quad * 8]);
        acc = MFMA16(af, bfrag[k], acc);
      }
      float at[4], rmx[4], rmy[4];
#pragma unroll
      for (int r = 0; r < 4; r++) {
        float2 rm = stats_lds[rowbase + quad * 4 + r];
        rmx[r] = rm.x; rmy[r] = rm.y;
        float lg = rm.x * acc[r] + rm.y * cdv.x + cdv.y;
        float mx = lg;
        mx = fmaxf(mx, __shfl_xor(mx, 1));
        mx = fmaxf(mx, __shfl_xor(mx, 2));
        mx = fmaxf(mx, __shfl_xor(mx, 4));
        float e = __expf(lg - mx);
        float sm = e;
        sm += __shfl_xor(sm, 1); sm += __shfl_xor(sm, 2); sm += __shfl_xor(sm, 4);
        at[r] = e / sm;
      }
      if (col < 8) {
#pragma unroll
        for (int r = 0; r < 4; r++) {
          int n_loc = rowbase + quad * 4 + r;
          out_attn[(size_t)(b * 8 + col) * 4096 + nb + n_loc] = at[r];
          a2t[col][n_loc] = f2bf(at[r] * rmx[r]);  // a2 = attn*rstd
          s0a += at[r];
          s1a += at[r] * rmy[r];
        }
      }
    }
    __syncthreads();
    // phase B (all 8 waves): Y[s][i] += a2t @ x  via MFMA; 2 i-tiles per wave
    {
      bf16x8 af0 = *reinterpret_cast<const bf16x8*>(&a2t[col][quad * 8]);
      bf16x8 af1 = *reinterpret_cast<const bf16x8*>(&a2t[col][32 + quad * 8]);
#pragma unroll
      for (int cc = 0; cc < 2; cc++) {
        int ib = (wave * 2 + cc) * 16 + col;
        union { short s[8]; bf16x8 v; } b0, b1;
#pragma unroll
        for (int j = 0; j < 8; j++) {
          b0.s[j] = (short)x_lds[quad * 8 + j][ib];
          b1.s[j] = (short)x_lds[32 + quad * 8 + j][ib];
        }
        Yacc[cc] = MFMA16(af0, b0.v, Yacc[cc]);
        Yacc[cc] = MFMA16(af1, b1.v, Yacc[cc]);
      }
    }
    __syncthreads();
  }
  // epilogue: store Y partials (D rows 0..7 live in quads 0..1)
  if (quad < 2) {
#pragma unroll
    for (int cc = 0; cc < 2; cc++) {
      int i = (wave * 2 + cc) * 16 + col;
#pragma unroll
      for (int r = 0; r < 4; r++) {
        int s = quad * 4 + r;
        wsY[(size_t)((b * 8 + chunk) * 8 + s) * 256 + i] = Yacc[cc][r];
      }
    }
  }
  s0a += __shfl_xor(s0a, 16); s0a += __shfl_xor(s0a, 32);
  s1a += __shfl_xor(s1a, 16); s1a += __shfl_xor(s1a, 32);
  if (wave < 4 && lane < 8) red2[wave][lane] = make_float2(s0a, s1a);
  __syncthreads();
  if (tid < 8) {
    float S0 = 0.f, S1 = 0.f;
#pragma unroll
    for (int w = 0; w < 4; w++) { S0 += red2[w][tid].x; S1 += red2[w][tid].y; }
    wsS[((b * 8 + chunk) * 8 + tid) * 2 + 0] = S0;
    wsS[((b * 8 + chunk) * 8 + tid) * 2 + 1] = S1;
  }
}

// ---------------------------------------------------------------- launch
extern "C" void kernel_launch(void* const* d_in, const int* in_sizes, int n_in,
                              void* d_out, int out_size, void* d_ws, size_t ws_size,
                              hipStream_t stream) {
  const float* inputs = (const float*)d_in[0];
  const float* noise = (const float*)d_in[1];
  const float* s_mu = (const float*)d_in[2];
  const float* s_ls = (const float*)d_in[3];
  const float* g_in = (const float*)d_in[4];
  const float* b_in = (const float*)d_in[5];
  const float* g_s = (const float*)d_in[6];
  const float* b_s = (const float*)d_in[7];
  const float* g_m = (const float*)d_in[8];
  const float* b_m = (const float*)d_in[9];
  const float* Wq = (const float*)d_in[10];
  const float* Wk = (const float*)d_in[11];
  const float* Wv = (const float*)d_in[12];
  const float* wih = (const float*)d_in[13];
  const float* whh = (const float*)d_in[14];
  const float* bih = (const float*)d_in[15];
  const float* bhh = (const float*)d_in[16];
  const float* w1 = (const float*)d_in[17];
  const float* b1v = (const float*)d_in[18];
  const float* w2 = (const float*)d_in[19];
  const float* b2v = (const float*)d_in[20];
  float* out = (float*)d_out;

  size_t o = 0;
  auto take = [&](size_t bytes) {
    void* p = (char*)d_ws + o;
    o += (bytes + 255) & ~(size_t)255;
    return p;
  };
  float* slots = (float*)take((size_t)64 * 8 * 256 * 4);
  u16* qg = (u16*)take((size_t)64 * 16 * 256 * 2);
  float* cd = (float*)take((size_t)64 * 16 * 2 * 4);
  float* wsY = (float*)take((size_t)64 * 8 * 8 * 256 * 4);
  float* wsS = (float*)take((size_t)64 * 8 * 8 * 2 * 4);
  u16* wkB = (u16*)take((size_t)65536 * 2);
  u16* wqT = (u16*)take((size_t)65536 * 2);
  u16* wvT = (u16*)take((size_t)65536 * 2);
  u16* wihB = (u16*)take((size_t)196608 * 2);
  u16* whhB = (u16*)take((size_t)196608 * 2);
  u16* w1T = (u16*)take((size_t)262144 * 2);
  u16* w2T = (u16*)take((size_t)262144 * 2);

  prep_kernel<<<256, 256, 0, stream>>>(Wq, Wk, Wv, wih, whh, w1, w2,
                                       wkB, wqT, wvT, wihB, whhB, w1T, w2T);
  slot_kernel<<<64, 1024, 0, stream>>>(slots, qg, cd, wsY, wsS,
                                       wvT, wihB, whhB, w1T, w2T, wqT, wkB,
                                       bih, bhh, b1v, b2v,
                                       g_in, b_in, g_s, b_s, g_m, b_m,
                                       s_mu, s_ls, noise, out, 0);
  for (int it = 0; it < 3; it++) {
    attn_kernel<<<dim3(8, 64), 512, 0, stream>>>(inputs, qg, cd, out, wsY, wsS);
    slot_kernel<<<64, 1024, 0, stream>>>(slots, qg, cd, wsY, wsS,
                                         wvT, wihB, whhB, w1T, w2T, wqT, wkB,
                                         bih, bhh, b1v, b2v,
                                         g_in, b_in, g_s, b_s, g_m, b_m,
                                         s_mu, s_ls, noise, out, 1);
  }
}

// Round 3
// 701.861 us; speedup vs baseline: 1.4430x; 1.1015x over previous
//
#include <hip/hip_runtime.h>

// SlotAttention on MI355X (gfx950).
// Never materialize k/v:
//   logits[n,s] = rstd_n*(x_n . qg_s) + (rstd_n*mu_n)*c_s + d_s   (qg = g*(Wk q)/16, MFMA bf16)
//   Y[s,i]      = sum_n attn[n,s]*rstd_n*x[n,i]                   (MFMA: A=a2^T, B=x columns)
//   updates     = (g*(Y-S1) + b*S0)/(S0+1e-8) @ Wv                (tiny MFMA)
// R3: attn pass 0 caches bf16 x + row stats in ws; passes 1-2 skip fp32 read + LN stats.
//     Group loads prefetched before phase A/B (latency overlap). LDS-tiled prep transpose.

typedef unsigned short u16;
typedef __attribute__((ext_vector_type(8))) short bf16x8;
typedef __attribute__((ext_vector_type(4))) float f32x4;

#define MFMA16(a, b, c) __builtin_amdgcn_mfma_f32_16x16x32_bf16((a), (b), (c), 0, 0, 0)

__device__ __forceinline__ u16 f2bf(float f) {
  union { float f; unsigned u; } v; v.f = f;
  unsigned r = (v.u + 0x7fffu + ((v.u >> 16) & 1u)) >> 16;
  return (u16)r;
}
__device__ __forceinline__ float sigm(float x) { return 1.f / (1.f + __expf(-x)); }
__device__ __forceinline__ float tanh_f(float x) { return 1.f - 2.f / (1.f + __expf(2.f * x)); }

// ---------------------------------------------------------------- prep: LDS-tiled transpose + casts
// blocks 0..159: 64x64 transpose tiles. blocks 160..223: straight casts.
__global__ __launch_bounds__(256) void prep_kernel(
    const float* __restrict__ Wq, const float* __restrict__ Wk, const float* __restrict__ Wv,
    const float* __restrict__ wih, const float* __restrict__ whh,
    const float* __restrict__ w1, const float* __restrict__ w2,
    u16* __restrict__ wkB, u16* __restrict__ wqT, u16* __restrict__ wvT,
    u16* __restrict__ wihB, u16* __restrict__ whhB, u16* __restrict__ w1T, u16* __restrict__ w2T) {
  const int bid = blockIdx.x;
  const int tid = threadIdx.x;
  if (bid < 160) {
    // dst[R][C], dst[i][j] = src[j][i]; src is C rows x R cols
    __shared__ float tile[64][65];
    const float* src; u16* dst; int R, C, t;
    if (bid < 16)      { src = Wq; dst = wqT; R = 256;  C = 256;  t = bid; }
    else if (bid < 32) { src = Wv; dst = wvT; R = 256;  C = 256;  t = bid - 16; }
    else if (bid < 96) { src = w1; dst = w1T; R = 1024; C = 256;  t = bid - 32; }
    else               { src = w2; dst = w2T; R = 256;  C = 1024; t = bid - 96; }
    const int tilesJ = C >> 6;
    const int i0 = (t / tilesJ) * 64, j0 = (t % tilesJ) * 64;
    const int c = tid & 63, r0 = tid >> 6;
#pragma unroll
    for (int rr = 0; rr < 16; rr++) {
      int row = rr * 4 + r0;
      tile[row][c] = src[(size_t)(j0 + row) * R + i0 + c];  // coalesced read
    }
    __syncthreads();
#pragma unroll
    for (int rr = 0; rr < 16; rr++) {
      int row = rr * 4 + r0;
      dst[(size_t)(i0 + row) * C + j0 + c] = f2bf(tile[c][row]);  // coalesced write
    }
  } else {
    // straight casts: wk (65536), wih (196608), whh (196608) -> 458752 elems, float4 granules
    int gid = (bid - 160) * 256 + tid;
    for (int i4 = gid; i4 < 114688; i4 += 64 * 256) {
      int i = i4 * 4;
      const float* s; u16* d; int off;
      if (i < 65536) { s = Wk; d = wkB; off = i; }
      else if (i < 262144) { s = wih; d = wihB; off = i - 65536; }
      else { s = whh; d = whhB; off = i - 262144; }
      float4 v = *reinterpret_cast<const float4*>(s + off);
      unsigned lo = (unsigned)f2bf(v.x) | ((unsigned)f2bf(v.y) << 16);
      unsigned hi = (unsigned)f2bf(v.z) | ((unsigned)f2bf(v.w) << 16);
      *reinterpret_cast<uint2*>(d + off) = make_uint2(lo, hi);
    }
  }
}

// ---------------------------------------------------------------- per-wave LN of one row (wave=row), rows 8..15 zeroed
__device__ __forceinline__ void ln_row16(const float (*src)[264], u16 (*dst)[264],
                                         const float* __restrict__ g, const float* __restrict__ bb,
                                         int wave, int lane) {
  int row = wave;
  if (row < 8) {
    float4 v = *reinterpret_cast<const float4*>(&src[row][lane * 4]);
    float s = v.x + v.y + v.z + v.w;
    float sq = v.x * v.x + v.y * v.y + v.z * v.z + v.w * v.w;
#pragma unroll
    for (int m = 1; m < 64; m <<= 1) { s += __shfl_xor(s, m); sq += __shfl_xor(sq, m); }
    float mu = s * (1.f / 256.f);
    float var = sq * (1.f / 256.f) - mu * mu;
    float rstd = rsqrtf(fmaxf(var, 0.f) + 1e-5f);
    float4 gg = *reinterpret_cast<const float4*>(&g[lane * 4]);
    float4 bv = *reinterpret_cast<const float4*>(&bb[lane * 4]);
    unsigned lo = (unsigned)f2bf((v.x - mu) * rstd * gg.x + bv.x) |
                  ((unsigned)f2bf((v.y - mu) * rstd * gg.y + bv.y) << 16);
    unsigned hi = (unsigned)f2bf((v.z - mu) * rstd * gg.z + bv.z) |
                  ((unsigned)f2bf((v.w - mu) * rstd * gg.w + bv.w) << 16);
    *reinterpret_cast<uint2*>(&dst[row][lane * 4]) = make_uint2(lo, hi);
  } else if (row < 16) {
    *reinterpret_cast<uint2*>(&dst[row][lane * 4]) = make_uint2(0, 0);
  }
}

// ---------------------------------------------------------------- slot kernel: one block (1024 thr, 16 waves) per batch
__global__ __launch_bounds__(1024, 4) void slot_kernel(
    float* __restrict__ slots, u16* __restrict__ qg, float* __restrict__ cd,
    const float* __restrict__ wsY, const float* __restrict__ wsS,
    const u16* __restrict__ wvT, const u16* __restrict__ wihB, const u16* __restrict__ whhB,
    const u16* __restrict__ w1T, const u16* __restrict__ w2T, const u16* __restrict__ wqT,
    const u16* __restrict__ wkB,
    const float* __restrict__ bih, const float* __restrict__ bhh,
    const float* __restrict__ b1v, const float* __restrict__ b2v,
    const float* __restrict__ g_in, const float* __restrict__ b_in,
    const float* __restrict__ g_s, const float* __restrict__ b_s,
    const float* __restrict__ g_m, const float* __restrict__ b_m,
    const float* __restrict__ s_mu, const float* __restrict__ s_ls,
    const float* __restrict__ noise,
    float* __restrict__ d_out, int do_update) {
  __shared__ alignas(16) char pool[58368];
  u16 (*h_lds)[1032] = reinterpret_cast<u16(*)[1032]>(pool);            // 33024 (P5->P6)
  u16 (*u_lds)[264] = reinterpret_cast<u16(*)[264]>(pool);              // alias h (P1->P2)
  u16 (*uv_lds)[264] = reinterpret_cast<u16(*)[264]>(pool + 8448);      // alias h (P2->P3)
  u16 (*sb_lds)[264] = reinterpret_cast<u16(*)[264]>(pool + 16896);     // alias h (P0->P3)
  u16 (*m_lds)[264] = reinterpret_cast<u16(*)[264]>(pool + 33024);      // 8448 (P4->P5, reused P7->P9)
  float (*ns_lds)[264] = reinterpret_cast<float(*)[264]>(pool + 41472); // 16896 (P3->P7)
  u16 (*q_lds)[264] = reinterpret_cast<u16(*)[264]>(pool + 41472);      // alias ns (P8->P9)
  __shared__ float sS0[16], sS1[16], sInv[16];
  __shared__ float redq[16][4][4][2];

  const int b = blockIdx.x;
  const int tid = threadIdx.x;
  const int lane = tid & 63, wave = tid >> 6;
  const int quad = lane >> 4, col = lane & 15;
  const int i256 = tid & 255, s4 = tid >> 8;
  const f32x4 vzero = {0.f, 0.f, 0.f, 0.f};

  if (do_update) {
    // P0: reduce S partials; stage slots as bf16
    if (tid < 16) {
      float S0 = 0.f, S1 = 0.f;
      if (tid < 8) {
        for (int c = 0; c < 8; c++) {
          S0 += wsS[((b * 8 + c) * 8 + tid) * 2 + 0];
          S1 += wsS[((b * 8 + c) * 8 + tid) * 2 + 1];
        }
      }
      sS0[tid] = S0; sS1[tid] = S1; sInv[tid] = 1.f / (S0 + 1e-8f);
    }
#pragma unroll
    for (int r = 0; r < 4; r++) {
      int s = s4 + r * 4;
      sb_lds[s][i256] = (s < 8) ? f2bf(slots[(size_t)(b * 8 + s) * 256 + i256]) : (u16)0;
    }
    __syncthreads();
    // P1: u_hat (I-space updates)
    {
      float gv = g_in[i256], bv = b_in[i256];
#pragma unroll
      for (int r = 0; r < 4; r++) {
        int s = s4 + r * 4;
        if (s < 8) {
          float y = 0.f;
#pragma unroll
          for (int c = 0; c < 8; c++) y += wsY[((size_t)((b * 8 + c) * 8 + s)) * 256 + i256];
          u_lds[s][i256] = f2bf((gv * (y - sS1[s]) + bv * sS0[s]) * sInv[s]);
        } else {
          u_lds[s][i256] = 0;
        }
      }
    }
    __syncthreads();
    // P2: updates_v = u_hat @ Wv (one 16-col tile per wave)
    {
      bf16x8 af[8];
#pragma unroll
      for (int k = 0; k < 8; k++)
        af[k] = *reinterpret_cast<const bf16x8*>(&u_lds[col][k * 32 + quad * 8]);
      int ct = wave;
      f32x4 acc = vzero;
#pragma unroll
      for (int k = 0; k < 8; k++) {
        bf16x8 bf = *reinterpret_cast<const bf16x8*>(wvT + (size_t)(ct * 16 + col) * 256 + k * 32 + quad * 8);
        acc = MFMA16(af[k], bf, acc);
      }
#pragma unroll
      for (int r = 0; r < 4; r++) {
        int s = quad * 4 + r;
        uv_lds[s][ct * 16 + col] = (s < 8) ? f2bf(acc[r]) : (u16)0;
      }
    }
    __syncthreads();
    // P3: gi/gh GEMMs + GRU elementwise -> ns_lds (one d-tile per wave)
    {
      bf16x8 afu[8], afs[8];
#pragma unroll
      for (int k = 0; k < 8; k++) {
        afu[k] = *reinterpret_cast<const bf16x8*>(&uv_lds[col][k * 32 + quad * 8]);
        afs[k] = *reinterpret_cast<const bf16x8*>(&sb_lds[col][k * 32 + quad * 8]);
      }
      int d = wave * 16 + col;
      f32x4 a_ir = vzero, a_iz = vzero, a_in = vzero, a_hr = vzero, a_hz = vzero, a_hn = vzero;
#pragma unroll
      for (int k = 0; k < 8; k++) {
        int ko = k * 32 + quad * 8;
        a_ir = MFMA16(afu[k], *reinterpret_cast<const bf16x8*>(wihB + (size_t)(d)*256 + ko), a_ir);
        a_iz = MFMA16(afu[k], *reinterpret_cast<const bf16x8*>(wihB + (size_t)(256 + d) * 256 + ko), a_iz);
        a_in = MFMA16(afu[k], *reinterpret_cast<const bf16x8*>(wihB + (size_t)(512 + d) * 256 + ko), a_in);
        a_hr = MFMA16(afs[k], *reinterpret_cast<const bf16x8*>(whhB + (size_t)(d)*256 + ko), a_hr);
        a_hz = MFMA16(afs[k], *reinterpret_cast<const bf16x8*>(whhB + (size_t)(256 + d) * 256 + ko), a_hz);
        a_hn = MFMA16(afs[k], *reinterpret_cast<const bf16x8*>(whhB + (size_t)(512 + d) * 256 + ko), a_hn);
      }
      float bihr = bih[d], bihz = bih[256 + d], bihn = bih[512 + d];
      float bhhr = bhh[d], bhhz = bhh[256 + d], bhhn = bhh[512 + d];
#pragma unroll
      for (int r = 0; r < 4; r++) {
        int s = quad * 4 + r;
        float rg = sigm(a_ir[r] + bihr + a_hr[r] + bhhr);
        float zg = sigm(a_iz[r] + bihz + a_hz[r] + bhhz);
        float ng = tanh_f(a_in[r] + bihn + rg * (a_hn[r] + bhhn));
        float prev = (s < 8) ? slots[(size_t)(b * 8 + s) * 256 + d] : 0.f;
        float ns = (1.f - zg) * ng + zg * prev;
        ns_lds[s][d] = (s < 8) ? ns : 0.f;
      }
    }
    __syncthreads();
    // P4: LN_m -> m_lds
    ln_row16(ns_lds, m_lds, g_m, b_m, wave, lane);
    __syncthreads();
    // P5: mlp1 -> h_lds (relu), 4 tiles per wave
    {
      bf16x8 af[8];
#pragma unroll
      for (int k = 0; k < 8; k++)
        af[k] = *reinterpret_cast<const bf16x8*>(&m_lds[col][k * 32 + quad * 8]);
      for (int cc = 0; cc < 4; cc++) {
        int ct = wave * 4 + cc;
        f32x4 acc = vzero;
#pragma unroll
        for (int k = 0; k < 8; k++) {
          bf16x8 bf = *reinterpret_cast<const bf16x8*>(w1T + (size_t)(ct * 16 + col) * 256 + k * 32 + quad * 8);
          acc = MFMA16(af[k], bf, acc);
        }
        float bb = b1v[ct * 16 + col];
#pragma unroll
        for (int r = 0; r < 4; r++) {
          int s = quad * 4 + r;
          float h = fmaxf(acc[r] + bb, 0.f);
          h_lds[s][ct * 16 + col] = (s < 8) ? f2bf(h) : (u16)0;
        }
      }
    }
    __syncthreads();
    // P6: mlp2 + residual -> new slots (one tile per wave)
    {
      int ct = wave;
      f32x4 acc = vzero;
      for (int k = 0; k < 32; k++) {
        bf16x8 af = *reinterpret_cast<const bf16x8*>(&h_lds[col][k * 32 + quad * 8]);
        bf16x8 bf = *reinterpret_cast<const bf16x8*>(w2T + (size_t)(ct * 16 + col) * 1024 + k * 32 + quad * 8);
        acc = MFMA16(af, bf, acc);
      }
      int d = ct * 16 + col;
      float bb = b2v[d];
#pragma unroll
      for (int r = 0; r < 4; r++) {
        int s = quad * 4 + r;
        if (s < 8) {
          float fin = ns_lds[s][d] + acc[r] + bb;
          slots[(size_t)(b * 8 + s) * 256 + d] = fin;
          d_out[(size_t)(b * 8 + s) * 256 + d] = fin;
          ns_lds[s][d] = fin;
        }
      }
    }
    __syncthreads();
  } else {
    // init: slots = mu + exp(ls)*noise
#pragma unroll
    for (int r = 0; r < 4; r++) {
      int s = s4 + r * 4;
      float v = 0.f;
      if (s < 8) {
        v = s_mu[i256] + __expf(s_ls[i256]) * noise[(size_t)(b * 8 + s) * 256 + i256];
        slots[(size_t)(b * 8 + s) * 256 + i256] = v;
      }
      ns_lds[s][i256] = v;
    }
    __syncthreads();
  }

  // ---- TAIL: qg/cd for next attention pass ----
  // P7: LN_s -> m_lds
  ln_row16(ns_lds, m_lds, g_s, b_s, wave, lane);
  __syncthreads();
  // P8: q = s_n @ Wq -> q_lds (one tile per wave)
  {
    bf16x8 af[8];
#pragma unroll
    for (int k = 0; k < 8; k++)
      af[k] = *reinterpret_cast<const bf16x8*>(&m_lds[col][k * 32 + quad * 8]);
    int ct = wave;
    f32x4 acc = vzero;
#pragma unroll
    for (int k = 0; k < 8; k++) {
      bf16x8 bf = *reinterpret_cast<const bf16x8*>(wqT + (size_t)(ct * 16 + col) * 256 + k * 32 + quad * 8);
      acc = MFMA16(af[k], bf, acc);
    }
#pragma unroll
    for (int r = 0; r < 4; r++) {
      int s = quad * 4 + r;
      q_lds[s][ct * 16 + col] = (s < 8) ? f2bf(acc[r]) : (u16)0;
    }
  }
  __syncthreads();
  // P9: qk = q @ Wk-as-B; qg = g*qk/16; c = -sum qg; d = sum b*qk/16
  {
    bf16x8 af[8];
#pragma unroll
    for (int k = 0; k < 8; k++)
      af[k] = *reinterpret_cast<const bf16x8*>(&q_lds[col][k * 32 + quad * 8]);
    float cacc[4] = {0.f, 0.f, 0.f, 0.f}, dacc[4] = {0.f, 0.f, 0.f, 0.f};
    int ct = wave;
    f32x4 acc = vzero;
#pragma unroll
    for (int k = 0; k < 8; k++) {
      bf16x8 bf = *reinterpret_cast<const bf16x8*>(wkB + (size_t)(ct * 16 + col) * 256 + k * 32 + quad * 8);
      acc = MFMA16(af[k], bf, acc);
    }
    int i = ct * 16 + col;
    float gi_ = g_in[i] * 0.0625f, bi_ = b_in[i] * 0.0625f;
#pragma unroll
    for (int r = 0; r < 4; r++) {
      int s = quad * 4 + r;
      float qkv = acc[r];
      float qgv = (s < 8) ? gi_ * qkv : 0.f;
      qg[(size_t)(b * 16 + s) * 256 + i] = f2bf(qgv);
      cacc[r] -= qgv;
      dacc[r] += (s < 8) ? bi_ * qkv : 0.f;
    }
#pragma unroll
    for (int r = 0; r < 4; r++) {
#pragma unroll
      for (int m = 1; m < 16; m <<= 1) {
        cacc[r] += __shfl_xor(cacc[r], m);
        dacc[r] += __shfl_xor(dacc[r], m);
      }
    }
    if (col == 0) {
#pragma unroll
      for (int r = 0; r < 4; r++) {
        redq[wave][quad][r][0] = cacc[r];
        redq[wave][quad][r][1] = dacc[r];
      }
    }
    __syncthreads();
    if (tid < 16) {
      int qd = tid >> 2, r = tid & 3;
      float c = 0.f, dd = 0.f;
      for (int w = 0; w < 16; w++) { c += redq[w][qd][r][0]; dd += redq[w][qd][r][1]; }
      cd[(b * 16 + tid) * 2 + 0] = c;
      cd[(b * 16 + tid) * 2 + 1] = dd;
    }
  }
}

// ---------------------------------------------------------------- attention kernel
// grid (8 chunks, 64 batches), 512 threads (8 waves). Each block: 512 n's in 8 groups of 64.
// PASS 0: read fp32 x, compute stats, write xb (bf16) + stats2 to ws.
// PASS 1: read xb + stats2 (cheap staging, half HBM bytes, largely L3-resident).
template <int PASS>
__global__ __launch_bounds__(512, 4) void attn_kernel(
    const float* __restrict__ x, u16* __restrict__ xb, float2* __restrict__ stats2,
    const u16* __restrict__ qg, const float* __restrict__ cd,
    float* __restrict__ out, float* __restrict__ wsY, float* __restrict__ wsS) {
  __shared__ alignas(16) u16 x_lds[64][264];
  __shared__ alignas(16) u16 a2t[16][72];   // a2^T: [slot][n_local], bf16
  __shared__ float2 stats_lds[64];
  __shared__ float2 red2[4][8];

  const int chunk = blockIdx.x, b = blockIdx.y;
  const int tid = threadIdx.x;
  const int lane = tid & 63, wave = tid >> 6;   // 8 waves
  const int quad = lane >> 4, col = lane & 15;

  // zero a2t rows 8..15 once (A-fragment garbage rows benign-by-construction)
  for (int idx = tid; idx < 288; idx += 512)
    reinterpret_cast<unsigned*>(&a2t[8][0])[idx] = 0;

  // hoist q-fragments (phase A B-operand) + per-slot scalars
  bf16x8 bfrag[8];
#pragma unroll
  for (int k = 0; k < 8; k++)
    bfrag[k] = *reinterpret_cast<const bf16x8*>(qg + (size_t)(b * 16 + col) * 256 + k * 32 + quad * 8);
  const float2 cdv = *reinterpret_cast<const float2*>(cd + (b * 16 + col) * 2);

  f32x4 Yacc[2];
  Yacc[0] = {0.f, 0.f, 0.f, 0.f};
  Yacc[1] = {0.f, 0.f, 0.f, 0.f};
  float s0a = 0.f, s1a = 0.f;
  float* out_attn = out + 131072;

  // prefetch registers (one group ahead; issued before phase A/B so latency overlaps compute)
  float4 pf0[8];
  uint2 pf1[8];
  float2 pfs;
  {
    const int nb0 = chunk * 512;
    if (PASS == 0) {
#pragma unroll
      for (int p = 0; p < 8; p++)
        pf0[p] = *reinterpret_cast<const float4*>(x + (size_t)(b * 4096 + nb0 + wave * 8 + p) * 256 + lane * 4);
    } else {
#pragma unroll
      for (int p = 0; p < 8; p++)
        pf1[p] = *reinterpret_cast<const uint2*>(xb + (size_t)(b * 4096 + nb0 + wave * 8 + p) * 256 + lane * 4);
      if (tid < 64) pfs = stats2[(size_t)b * 4096 + nb0 + tid];
    }
  }

  for (int g = 0; g < 8; g++) {
    const int nb = chunk * 512 + g * 64;
    __syncthreads();  // phase B of g-1 done with x_lds/a2t
    // ---- staging: registers -> LDS (+ stats) ----
    if (PASS == 0) {
#pragma unroll
      for (int p = 0; p < 8; p++) {
        int row = wave * 8 + p;
        float4 v = pf0[p];
        float s = v.x + v.y + v.z + v.w;
        float sq = v.x * v.x + v.y * v.y + v.z * v.z + v.w * v.w;
#pragma unroll
        for (int m = 1; m < 64; m <<= 1) { s += __shfl_xor(s, m); sq += __shfl_xor(sq, m); }
        float mu = s * (1.f / 256.f);
        float var = sq * (1.f / 256.f) - mu * mu;
        float rstd = rsqrtf(fmaxf(var, 0.f) + 1e-5f);
        float2 st = make_float2(rstd, rstd * mu);
        if (lane == 0) {
          stats_lds[row] = st;
          stats2[(size_t)b * 4096 + nb + row] = st;
        }
        unsigned lo = (unsigned)f2bf(v.x) | ((unsigned)f2bf(v.y) << 16);
        unsigned hi = (unsigned)f2bf(v.z) | ((unsigned)f2bf(v.w) << 16);
        *reinterpret_cast<uint2*>(&x_lds[row][lane * 4]) = make_uint2(lo, hi);
        *reinterpret_cast<uint2*>(xb + (size_t)(b * 4096 + nb + row) * 256 + lane * 4) = make_uint2(lo, hi);
      }
    } else {
#pragma unroll
      for (int p = 0; p < 8; p++) {
        int row = wave * 8 + p;
        *reinterpret_cast<uint2*>(&x_lds[row][lane * 4]) = pf1[p];
      }
      if (tid < 64) stats_lds[tid] = pfs;
    }
    __syncthreads();
    // ---- prefetch next group (overlaps phase A + B) ----
    if (g < 7) {
      const int nbn = nb + 64;
      if (PASS == 0) {
#pragma unroll
        for (int p = 0; p < 8; p++)
          pf0[p] = *reinterpret_cast<const float4*>(x + (size_t)(b * 4096 + nbn + wave * 8 + p) * 256 + lane * 4);
      } else {
#pragma unroll
        for (int p = 0; p < 8; p++)
          pf1[p] = *reinterpret_cast<const uint2*>(xb + (size_t)(b * 4096 + nbn + wave * 8 + p) * 256 + lane * 4);
        if (tid < 64) pfs = stats2[(size_t)b * 4096 + nbn + tid];
      }
    }
    // ---- phase A (waves 0..3): logits MFMA + softmax + attn out + a2t ----
    if (wave < 4) {
      const int rowbase = wave * 16;
      f32x4 acc = {0.f, 0.f, 0.f, 0.f};
#pragma unroll
      for (int k = 0; k < 8; k++) {
        bf16x8 af = *reinterpret_cast<const bf16x8*>(&x_lds[rowbase + col][k * 32 + quad * 8]);
        acc = MFMA16(af, bfrag[k], acc);
      }
      float at[4], rmx[4], rmy[4];
#pragma unroll
      for (int r = 0; r < 4; r++) {
        float2 rm = stats_lds[rowbase + quad * 4 + r];
        rmx[r] = rm.x; rmy[r] = rm.y;
        float lg = rm.x * acc[r] + rm.y * cdv.x + cdv.y;
        float mx = lg;
        mx = fmaxf(mx, __shfl_xor(mx, 1));
        mx = fmaxf(mx, __shfl_xor(mx, 2));
        mx = fmaxf(mx, __shfl_xor(mx, 4));
        float e = __expf(lg - mx);
        float sm = e;
        sm += __shfl_xor(sm, 1); sm += __shfl_xor(sm, 2); sm += __shfl_xor(sm, 4);
        at[r] = e / sm;
      }
      if (col < 8) {
#pragma unroll
        for (int r = 0; r < 4; r++) {
          int n_loc = rowbase + quad * 4 + r;
          out_attn[(size_t)(b * 8 + col) * 4096 + nb + n_loc] = at[r];
          a2t[col][n_loc] = f2bf(at[r] * rmx[r]);  // a2 = attn*rstd
          s0a += at[r];
          s1a += at[r] * rmy[r];
        }
      }
    }
    __syncthreads();
    // ---- phase B (all 8 waves): Y[s][i] += a2t @ x via MFMA; 2 i-tiles per wave ----
    {
      bf16x8 af0 = *reinterpret_cast<const bf16x8*>(&a2t[col][quad * 8]);
      bf16x8 af1 = *reinterpret_cast<const bf16x8*>(&a2t[col][32 + quad * 8]);
#pragma unroll
      for (int cc = 0; cc < 2; cc++) {
        int ib = (wave * 2 + cc) * 16 + col;
        union { short s[8]; bf16x8 v; } b0, b1;
#pragma unroll
        for (int j = 0; j < 8; j++) {
          b0.s[j] = (short)x_lds[quad * 8 + j][ib];
          b1.s[j] = (short)x_lds[32 + quad * 8 + j][ib];
        }
        Yacc[cc] = MFMA16(af0, b0.v, Yacc[cc]);
        Yacc[cc] = MFMA16(af1, b1.v, Yacc[cc]);
      }
    }
  }
  // epilogue: store Y partials (D rows 0..7 live in quads 0..1)
  if (quad < 2) {
#pragma unroll
    for (int cc = 0; cc < 2; cc++) {
      int i = (wave * 2 + cc) * 16 + col;
#pragma unroll
      for (int r = 0; r < 4; r++) {
        int s = quad * 4 + r;
        wsY[(size_t)((b * 8 + chunk) * 8 + s) * 256 + i] = Yacc[cc][r];
      }
    }
  }
  s0a += __shfl_xor(s0a, 16); s0a += __shfl_xor(s0a, 32);
  s1a += __shfl_xor(s1a, 16); s1a += __shfl_xor(s1a, 32);
  if (wave < 4 && lane < 8) red2[wave][lane] = make_float2(s0a, s1a);
  __syncthreads();
  if (tid < 8) {
    float S0 = 0.f, S1 = 0.f;
#pragma unroll
    for (int w = 0; w < 4; w++) { S0 += red2[w][tid].x; S1 += red2[w][tid].y; }
    wsS[((b * 8 + chunk) * 8 + tid) * 2 + 0] = S0;
    wsS[((b * 8 + chunk) * 8 + tid) * 2 + 1] = S1;
  }
}

// ---------------------------------------------------------------- launch
extern "C" void kernel_launch(void* const* d_in, const int* in_sizes, int n_in,
                              void* d_out, int out_size, void* d_ws, size_t ws_size,
                              hipStream_t stream) {
  const float* inputs = (const float*)d_in[0];
  const float* noise = (const float*)d_in[1];
  const float* s_mu = (const float*)d_in[2];
  const float* s_ls = (const float*)d_in[3];
  const float* g_in = (const float*)d_in[4];
  const float* b_in = (const float*)d_in[5];
  const float* g_s = (const float*)d_in[6];
  const float* b_s = (const float*)d_in[7];
  const float* g_m = (const float*)d_in[8];
  const float* b_m = (const float*)d_in[9];
  const float* Wq = (const float*)d_in[10];
  const float* Wk = (const float*)d_in[11];
  const float* Wv = (const float*)d_in[12];
  const float* wih = (const float*)d_in[13];
  const float* whh = (const float*)d_in[14];
  const float* bih = (const float*)d_in[15];
  const float* bhh = (const float*)d_in[16];
  const float* w1 = (const float*)d_in[17];
  const float* b1v = (const float*)d_in[18];
  const float* w2 = (const float*)d_in[19];
  const float* b2v = (const float*)d_in[20];
  float* out = (float*)d_out;

  size_t o = 0;
  auto take = [&](size_t bytes) {
    void* p = (char*)d_ws + o;
    o += (bytes + 255) & ~(size_t)255;
    return p;
  };
  float* slots = (float*)take((size_t)64 * 8 * 256 * 4);
  u16* qg = (u16*)take((size_t)64 * 16 * 256 * 2);
  float* cd = (float*)take((size_t)64 * 16 * 2 * 4);
  float* wsY = (float*)take((size_t)64 * 8 * 8 * 256 * 4);
  float* wsS = (float*)take((size_t)64 * 8 * 8 * 2 * 4);
  u16* wkB = (u16*)take((size_t)65536 * 2);
  u16* wqT = (u16*)take((size_t)65536 * 2);
  u16* wvT = (u16*)take((size_t)65536 * 2);
  u16* wihB = (u16*)take((size_t)196608 * 2);
  u16* whhB = (u16*)take((size_t)196608 * 2);
  u16* w1T = (u16*)take((size_t)262144 * 2);
  u16* w2T = (u16*)take((size_t)262144 * 2);
  u16* xb = (u16*)take((size_t)64 * 4096 * 256 * 2);      // 128 MiB bf16 x-cache
  float2* stats2 = (float2*)take((size_t)64 * 4096 * 8);  // per-row (rstd, rstd*mu)

  prep_kernel<<<224, 256, 0, stream>>>(Wq, Wk, Wv, wih, whh, w1, w2,
                                       wkB, wqT, wvT, wihB, whhB, w1T, w2T);
  slot_kernel<<<64, 1024, 0, stream>>>(slots, qg, cd, wsY, wsS,
                                       wvT, wihB, whhB, w1T, w2T, wqT, wkB,
                                       bih, bhh, b1v, b2v,
                                       g_in, b_in, g_s, b_s, g_m, b_m,
                                       s_mu, s_ls, noise, out, 0);
  for (int it = 0; it < 3; it++) {
    if (it == 0)
      attn_kernel<0><<<dim3(8, 64), 512, 0, stream>>>(inputs, xb, stats2, qg, cd, out, wsY, wsS);
    else
      attn_kernel<1><<<dim3(8, 64), 512, 0, stream>>>(inputs, xb, stats2, qg, cd, out, wsY, wsS);
    slot_kernel<<<64, 1024, 0, stream>>>(slots, qg, cd, wsY, wsS,
                                         wvT, wihB, whhB, w1T, w2T, wqT, wkB,
                                         bih, bhh, b1v, b2v,
                                         g_in, b_in, g_s, b_s, g_m, b_m,
                                         s_mu, s_ls, noise, out, 1);
  }
}